// Round 8
// baseline (184.098 us; speedup 1.0000x reference)
//
#include <hip/hip_runtime.h>
#include <hip/hip_bf16.h>
#include <math.h>

#define EPSV 1e-5f
#define AS1 __attribute__((address_space(1)))
#define AS3 __attribute__((address_space(3)))

typedef __attribute__((ext_vector_type(4))) float f32x4;
typedef __attribute__((ext_vector_type(8))) short bf16x8;
typedef __attribute__((ext_vector_type(4))) unsigned short u16x4;

__device__ __forceinline__ unsigned short f2b(float x) {
  union { float f; unsigned int u; } v; v.f = x;
  unsigned int r = v.u + 0x7FFFu + ((v.u >> 16) & 1u);
  return (unsigned short)(r >> 16);
}
__device__ __forceinline__ float b2f(unsigned short h) {
  union { float f; unsigned int u; } v; v.u = ((unsigned int)h) << 16;
  return v.f;
}

// block = 256 threads = 4 waves; sbuf must have 4 floats
__device__ __forceinline__ float block_reduce_sum(float v, float* sbuf) {
  #pragma unroll
  for (int off = 32; off; off >>= 1) v += __shfl_xor(v, off);
  __syncthreads();
  if ((threadIdx.x & 63) == 0) sbuf[threadIdx.x >> 6] = v;
  __syncthreads();
  return sbuf[0] + sbuf[1] + sbuf[2] + sbuf[3];
}

// ---------------- prep: V part (blk < BN) + SW part (blk >= BN) --------------
__global__ __launch_bounds__(256) void prep(const float* __restrict__ ctx,
                                            const float* __restrict__ wt,
                                            const float* __restrict__ speed,
                                            const float* __restrict__ uva,
                                            const float* __restrict__ accu,
                                            const float* __restrict__ accv,
                                            const float* __restrict__ uvaACC,
                                            const float* __restrict__ angle,
                                            const float* __restrict__ dist,
                                            unsigned short* __restrict__ V,
                                            unsigned short* __restrict__ SW,
                                            int BN, int N) {
  __shared__ float sbuf[4];
  const int blk = blockIdx.x;
  if (blk < BN) {
    const int bn = blk;
    const int w = threadIdx.x >> 6;
    const int lane = threadIdx.x & 63;
    const int p = w * 4 + (lane >> 4);
    const int dl = (lane & 15) * 8;
    const float* c = ctx + (size_t)bn * 128;
    const f32x4 ca = *(const f32x4*)(c + dl);
    const f32x4 cb = *(const f32x4*)(c + dl + 4);
    const f32x4 wa = *(const f32x4*)(wt + p * 128 + dl);
    const f32x4 wb = *(const f32x4*)(wt + p * 128 + dl + 4);
    float a[8];
    float ss = 0.0f;
    #pragma unroll
    for (int i = 0; i < 4; ++i) {
      a[i] = ca[i] * wa[i];
      a[4 + i] = cb[i] * wb[i];
      ss += a[i] * a[i] + a[4 + i] * a[4 + i];
    }
    ss += __shfl_xor(ss, 1);
    ss += __shfl_xor(ss, 2);
    ss += __shfl_xor(ss, 4);
    ss += __shfl_xor(ss, 8);
    const float inv = 1.0f / fmaxf(sqrtf(ss), 1e-12f);
    bf16x8 o;
    #pragma unroll
    for (int i = 0; i < 8; ++i) o[i] = (short)f2b(a[i] * inv);
    *(bf16x8*)(V + (size_t)bn * 2048 + p * 128 + dl) = o;
  } else {
    const int bn = blk - BN;
    const int n = bn & (N - 1);
    const int t = threadIdx.x;
    const float ua = uva[bn];
    const float sp = fabsf(speed[bn]);
    const float au = accu[bn], av = accv[bn];
    const float ta = sqrtf(au * au + av * av + EPSV) * fabsf(cosf(uvaACC[bn] - ua));
    const f32x4 an = *(const f32x4*)(angle + (size_t)n * N + 4 * t);
    const f32x4 dv = *(const f32x4*)(dist + (size_t)n * N + 4 * t);
    float v[4];
    float ss = 0.0f;
    #pragma unroll
    for (int i = 0; i < 4; ++i) {
      float cv = cosf(an[i] - ua);
      if (4 * t + i == n) cv += 0.5f * ta;
      v[i] = sp * fabsf(cv) / (dv[i] + EPSV);
      ss += v[i] * v[i];
    }
    ss = block_reduce_sum(ss, sbuf);
    const float inv = 1.0f / fmaxf(sqrtf(ss), 1e-12f);
    u16x4 o;
    #pragma unroll
    for (int i = 0; i < 4; ++i) o[i] = f2b(v[i] * inv);
    *(u16x4*)(SW + (size_t)bn * N + 4 * t) = o;
  }
}

// ---------------- merged uniform GEMM ----------------------------------------
// 512 blocks x 256 thr (4 waves). Block id: b = id&7 (XCD affinity), tile =
// id>>3 -> (m0,n0) in 8x8 grid of 128x128 tiles. Each block: att tile
// (V, K=2048, relu/16 -> OUT f32) THEN y tile (SW, K=1024, *0.07+EPS -> Yb
// bf16) at the same (b,m0,n0): identical work per block, zero tail.
// 3-buf LDS ring (48 KB -> 2 blocks/CU), ONE barrier per K-tile phase,
// counted vmcnt(4) (4 loads/thread/stage; never 0 mid-loop), compiler-managed
// fine-grained lgkmcnt for ds_read->MFMA. Both-sides chunk swizzle:
// c = pc ^ ((row>>1)&3) on global source and LDS read (conflicts = 0 proven).
// mode: 0 = both segments, 1 = att only, 2 = y only (split fallback).
#define FENCE asm volatile("" ::: "memory")
__device__ __forceinline__ void barx() { FENCE; __builtin_amdgcn_s_barrier(); FENCE; }

__global__ __launch_bounds__(256, 2) void gemm2(const unsigned short* __restrict__ V,
                                                const unsigned short* __restrict__ SW,
                                                float* __restrict__ OUT,
                                                unsigned short* __restrict__ Yb,
                                                int mode) {
  __shared__ __align__(16) unsigned short As[3][128 * 32];
  __shared__ __align__(16) unsigned short Bs[3][128 * 32];
  const int id = blockIdx.x;
  const int b = id & 7;
  const int tile = id >> 3;
  const int m0 = (tile & 7) * 128;
  const int n0 = (tile >> 3) * 128;
  const int tid = threadIdx.x;
  const int lane = tid & 63;
  const int wid = tid >> 6;            // 4 waves: 2 (M) x 2 (N)
  const int wm = (wid >> 1) * 64;
  const int wn = (wid & 1) * 64;
  const int fr = lane & 15;
  const int fc = lane >> 4;
  const int rsw = (fc ^ ((fr >> 1) & 3)) << 3;   // read swizzle (shorts)

  f32x4 acc[4][4];
  bf16x8 af[4], bf[4];

  auto runseg = [&](const unsigned short* Ab, int K) {
    #pragma unroll
    for (int i = 0; i < 4; ++i)
      #pragma unroll
      for (int j = 0; j < 4; ++j) acc[i][j] = f32x4{0.f, 0.f, 0.f, 0.f};

    auto stage = [&](int sb, int kt) {   // 4 loads/thread: A x2, B x2
      const int k0 = kt << 5;
      #pragma unroll
      for (int e = 0; e < 2; ++e) {
        const int idx = e * 256 + tid;   // 16B chunk id, 0..511
        const int row = idx >> 2;
        const int c = (idx & 3) ^ ((row >> 1) & 3);
        __builtin_amdgcn_global_load_lds(
            (const AS1 unsigned int*)(Ab + (size_t)(m0 + row) * K + k0 + (c << 3)),
            (AS3 unsigned int*)(&As[sb][idx * 8]), 16, 0, 0);
        __builtin_amdgcn_global_load_lds(
            (const AS1 unsigned int*)(Ab + (size_t)(n0 + row) * K + k0 + (c << 3)),
            (AS3 unsigned int*)(&Bs[sb][idx * 8]), 16, 0, 0);
      }
    };

    const int nk = K >> 5;
    stage(0, 0);
    stage(1, 1);
    asm volatile("s_waitcnt vmcnt(4)" ::: "memory");   // tile 0 resident
    barx();

    int rd = 0;
    for (int t = 0; t < nk; ++t) {
      if (t + 2 < nk) {
        int st = rd + 2; if (st >= 3) st -= 3;   // last read at t-1 -> safe now
        stage(st, t + 2);
      }
      const unsigned short* Ar = As[rd];
      const unsigned short* Br = Bs[rd];
      #pragma unroll
      for (int i = 0; i < 4; ++i)
        af[i] = *(const bf16x8*)(Ar + (wm + i * 16 + fr) * 32 + rsw);
      #pragma unroll
      for (int j = 0; j < 4; ++j)
        bf[j] = *(const bf16x8*)(Br + (wn + j * 16 + fr) * 32 + rsw);
      __builtin_amdgcn_s_setprio(1);
      #pragma unroll
      for (int i = 0; i < 4; ++i)
        #pragma unroll
        for (int j = 0; j < 4; ++j)
          acc[i][j] = __builtin_amdgcn_mfma_f32_16x16x32_bf16(af[i], bf[j], acc[i][j], 0, 0, 0);
      __builtin_amdgcn_s_setprio(0);
      if (t + 2 < nk)      { asm volatile("s_waitcnt vmcnt(4)" ::: "memory"); }  // t+1 resident
      else if (t + 1 < nk) { asm volatile("s_waitcnt vmcnt(0)" ::: "memory"); }
      barx();
      rd = (rd + 1 == 3) ? 0 : rd + 1;
    }
  };

  if (mode != 2) {
    runseg(V + (size_t)b * 1024 * 2048, 2048);
    float* Cb = OUT + (size_t)b * 1024 * 1024;
    #pragma unroll
    for (int i = 0; i < 4; ++i)
      #pragma unroll
      for (int rr = 0; rr < 4; ++rr) {
        const int row = m0 + wm + i * 16 + fc * 4 + rr;
        #pragma unroll
        for (int j = 0; j < 4; ++j) {
          const int col = n0 + wn + j * 16 + fr;
          Cb[(size_t)row * 1024 + col] = fmaxf(acc[i][j][rr] * (1.0f / 16.0f), 0.0f);
        }
      }
  }
  if (mode != 1) {
    runseg(SW + (size_t)b * 1024 * 1024, 1024);
    unsigned short* Cb = Yb + (size_t)b * 1024 * 1024;
    #pragma unroll
    for (int i = 0; i < 4; ++i)
      #pragma unroll
      for (int rr = 0; rr < 4; ++rr) {
        const int row = m0 + wm + i * 16 + fc * 4 + rr;
        #pragma unroll
        for (int j = 0; j < 4; ++j) {
          const int col = n0 + wn + j * 16 + fr;
          Cb[(size_t)row * 1024 + col] = f2b(acc[i][j][rr] * (1.4f / 20.0f) + EPSV);
        }
      }
  }
}

// ---------------- finisher: wave-per-row, no syncthreads ---------------------
// grid = BN/4 blocks x 256 thr; each wave owns one (b,n) row of 1024.
__global__ __launch_bounds__(256) void finkern(const unsigned short* __restrict__ Yb,
                                               const unsigned short* __restrict__ SW,
                                               float* __restrict__ OUT) {
  const int row = blockIdx.x * 4 + (threadIdx.x >> 6);   // 0..BN-1
  const int lane = threadIdx.x & 63;
  const unsigned short* y = Yb + (size_t)row * 1024;
  const unsigned short* sw = SW + (size_t)row * 1024;
  float* o = OUT + (size_t)row * 1024;

  float yv[16];
  float ss = 0.0f;
  #pragma unroll
  for (int ch = 0; ch < 4; ++ch) {
    const u16x4 yr = *(const u16x4*)(y + ch * 256 + lane * 4);
    #pragma unroll
    for (int i = 0; i < 4; ++i) {
      yv[ch * 4 + i] = b2f(yr[i]);
      ss += yv[ch * 4 + i] * yv[ch * 4 + i];
    }
  }
  #pragma unroll
  for (int off = 32; off; off >>= 1) ss += __shfl_xor(ss, off);
  const float invy = 1.0f / fmaxf(sqrtf(ss), 1e-12f);

  float tv[16];
  float st = 0.0f;
  #pragma unroll
  for (int ch = 0; ch < 4; ++ch) {
    const u16x4 sr = *(const u16x4*)(sw + ch * 256 + lane * 4);
    #pragma unroll
    for (int i = 0; i < 4; ++i) {
      const float x = fabsf(0.5f * b2f(sr[i]) + sqrtf(yv[ch * 4 + i] * invy)) + EPSV;
      tv[ch * 4 + i] = x;
      st += x * x;
    }
  }
  #pragma unroll
  for (int off = 32; off; off >>= 1) st += __shfl_xor(st, off);
  const float invt = 1.0f / fmaxf(sqrtf(st), 1e-12f);

  #pragma unroll
  for (int ch = 0; ch < 4; ++ch) {
    f32x4 ov = *(f32x4*)(o + ch * 256 + lane * 4);
    #pragma unroll
    for (int i = 0; i < 4; ++i) ov[i] *= tv[ch * 4 + i] * invt;
    *(f32x4*)(o + ch * 256 + lane * 4) = ov;
  }
}

extern "C" void kernel_launch(void* const* d_in, const int* in_sizes, int n_in,
                              void* d_out, int out_size, void* d_ws, size_t ws_size,
                              hipStream_t stream) {
  const float* ctx        = (const float*)d_in[0];
  const float* acc_u      = (const float*)d_in[1];
  const float* acc_v      = (const float*)d_in[2];
  const float* uv_angle   = (const float*)d_in[3];
  const float* uv_angleACC= (const float*)d_in[4];
  const float* speed      = (const float*)d_in[5];
  // d_in[6] = isPhy (unused by the reference computation)
  const float* dist       = (const float*)d_in[7];
  const float* angle      = (const float*)d_in[8];
  const float* wt         = (const float*)d_in[9];

  const int B = 8, N = 1024, P = 16;
  const int K1 = P * 128;  // 2048
  const int BN = B * N;    // 8192 rows

  const size_t szV  = (size_t)BN * K1 * 2;   // 33.5 MB bf16
  const size_t szSW = (size_t)BN * N * 2;    // 16.8 MB bf16
  const size_t szYb = (size_t)BN * N * 2;    // 16.8 MB bf16

  unsigned short* V  = (unsigned short*)d_ws;
  unsigned short* SW = (unsigned short*)((char*)d_ws + szV);
  float* out = (float*)d_out;

  prep<<<dim3(2 * BN), dim3(256), 0, stream>>>(ctx, wt, speed, uv_angle, acc_u,
                                               acc_v, uv_angleACC, angle, dist,
                                               V, SW, BN, N);

  if (ws_size >= szV + szSW + szYb) {
    // fused: 512 uniform blocks (att+y merged) = 2 resident blocks per CU
    unsigned short* Yp = (unsigned short*)((char*)d_ws + szV + szSW);
    gemm2<<<dim3(512), dim3(256), 0, stream>>>(V, SW, out, Yp, 0);
    finkern<<<dim3(BN / 4), dim3(256), 0, stream>>>(Yp, SW, out);
  } else {
    // split fallback: att pass first (consumes V), then y pass with Yb alias V
    unsigned short* Yp = (unsigned short*)d_ws;
    gemm2<<<dim3(512), dim3(256), 0, stream>>>(V, SW, out, Yp, 1);
    gemm2<<<dim3(512), dim3(256), 0, stream>>>(V, SW, out, Yp, 2);
    finkern<<<dim3(BN / 4), dim3(256), 0, stream>>>(Yp, SW, out);
  }
}

// Round 9
// 173.289 us; speedup vs baseline: 1.0624x; 1.0624x over previous
//
#include <hip/hip_runtime.h>
#include <hip/hip_bf16.h>
#include <math.h>

#define EPSV 1e-5f
#define AS1 __attribute__((address_space(1)))
#define AS3 __attribute__((address_space(3)))

typedef __attribute__((ext_vector_type(4))) float f32x4;
typedef __attribute__((ext_vector_type(8))) short bf16x8;
typedef __attribute__((ext_vector_type(4))) unsigned short u16x4;

__device__ __forceinline__ unsigned short f2b(float x) {
  union { float f; unsigned int u; } v; v.f = x;
  unsigned int r = v.u + 0x7FFFu + ((v.u >> 16) & 1u);
  return (unsigned short)(r >> 16);
}
__device__ __forceinline__ float b2f(unsigned short h) {
  union { float f; unsigned int u; } v; v.u = ((unsigned int)h) << 16;
  return v.f;
}

// block = 256 threads = 4 waves; sbuf must have 4 floats
__device__ __forceinline__ float block_reduce_sum(float v, float* sbuf) {
  #pragma unroll
  for (int off = 32; off; off >>= 1) v += __shfl_xor(v, off);
  __syncthreads();
  if ((threadIdx.x & 63) == 0) sbuf[threadIdx.x >> 6] = v;
  __syncthreads();
  return sbuf[0] + sbuf[1] + sbuf[2] + sbuf[3];
}

// ---------------- tabkern: CT/ST = cos/sin(angle) / (dist+EPS) ---------------
// N*N elements, 4 per thread -> 1024 blocks x 256 thr. Amortizes trig+div
// over B=8 batch rows (prep then does 2 FMAs/element instead of cosf+div).
__global__ __launch_bounds__(256) void tabkern(const float* __restrict__ angle,
                                               const float* __restrict__ dist,
                                               float* __restrict__ CT,
                                               float* __restrict__ ST) {
  const int i = (blockIdx.x * 256 + threadIdx.x) * 4;
  const f32x4 a = *(const f32x4*)(angle + i);
  const f32x4 d = *(const f32x4*)(dist + i);
  f32x4 ct, st;
  #pragma unroll
  for (int j = 0; j < 4; ++j) {
    const float inv = 1.0f / (d[j] + EPSV);
    float s, c;
    __sincosf(a[j], &s, &c);
    ct[j] = c * inv;
    st[j] = s * inv;
  }
  *(f32x4*)(CT + i) = ct;
  *(f32x4*)(ST + i) = st;
}

// ---------------- prep: V part (blk < BN) + SW part (blk >= BN) --------------
// V[b,n,p*128+d] = l2norm_d(context*w_p) bf16.
// SW[b,n,m] = l2norm_m( sp*|cu*CT + su*ST (+ diag)| ) bf16, via tables.
__global__ __launch_bounds__(256) void prep(const float* __restrict__ ctx,
                                            const float* __restrict__ wt,
                                            const float* __restrict__ speed,
                                            const float* __restrict__ uva,
                                            const float* __restrict__ accu,
                                            const float* __restrict__ accv,
                                            const float* __restrict__ uvaACC,
                                            const float* __restrict__ CT,
                                            const float* __restrict__ ST,
                                            const float* __restrict__ dist,
                                            unsigned short* __restrict__ V,
                                            unsigned short* __restrict__ SW,
                                            int BN, int N) {
  __shared__ float sbuf[4];
  const int blk = blockIdx.x;
  if (blk < BN) {
    const int bn = blk;
    const int w = threadIdx.x >> 6;
    const int lane = threadIdx.x & 63;
    const int p = w * 4 + (lane >> 4);
    const int dl = (lane & 15) * 8;
    const float* c = ctx + (size_t)bn * 128;
    const f32x4 ca = *(const f32x4*)(c + dl);
    const f32x4 cb = *(const f32x4*)(c + dl + 4);
    const f32x4 wa = *(const f32x4*)(wt + p * 128 + dl);
    const f32x4 wb = *(const f32x4*)(wt + p * 128 + dl + 4);
    float a[8];
    float ss = 0.0f;
    #pragma unroll
    for (int i = 0; i < 4; ++i) {
      a[i] = ca[i] * wa[i];
      a[4 + i] = cb[i] * wb[i];
      ss += a[i] * a[i] + a[4 + i] * a[4 + i];
    }
    ss += __shfl_xor(ss, 1);
    ss += __shfl_xor(ss, 2);
    ss += __shfl_xor(ss, 4);
    ss += __shfl_xor(ss, 8);
    const float inv = 1.0f / fmaxf(sqrtf(ss), 1e-12f);
    bf16x8 o;
    #pragma unroll
    for (int i = 0; i < 8; ++i) o[i] = (short)f2b(a[i] * inv);
    *(bf16x8*)(V + (size_t)bn * 2048 + p * 128 + dl) = o;
  } else {
    const int bn = blk - BN;
    const int n = bn & (N - 1);
    const int t = threadIdx.x;
    const float ua = uva[bn];
    float su, cu;
    __sincosf(ua, &su, &cu);
    const float sp = fabsf(speed[bn]);
    const float au = accu[bn], av = accv[bn];
    const float ta = sqrtf(au * au + av * av + EPSV) * fabsf(cosf(uvaACC[bn] - ua));
    // diagonal: (cosD + 0.5*ta) * inv_nn  ->  add 0.5*ta*inv_nn to cu*CT+su*ST
    const float diag = 0.5f * ta / (dist[(size_t)n * N + n] + EPSV);
    const f32x4 ct = *(const f32x4*)(CT + (size_t)n * N + 4 * t);
    const f32x4 st = *(const f32x4*)(ST + (size_t)n * N + 4 * t);
    float v[4];
    float ss = 0.0f;
    #pragma unroll
    for (int i = 0; i < 4; ++i) {
      float x = cu * ct[i] + su * st[i];
      if (4 * t + i == n) x += diag;
      v[i] = sp * fabsf(x);
      ss += v[i] * v[i];
    }
    ss = block_reduce_sum(ss, sbuf);
    const float inv = 1.0f / fmaxf(sqrtf(ss), 1e-12f);
    u16x4 o;
    #pragma unroll
    for (int i = 0; i < 4; ++i) o[i] = f2b(v[i] * inv);
    *(u16x4*)(SW + (size_t)bn * N + 4 * t) = o;
  }
}

// ---------------- 8-wave 128x256 GEMM (Round-5 proven: 56 us) ----------------
// id<256: att tile (V, K=2048, relu/16 -> OUT f32).
// id>=256: y tile (SW, K=1024, *0.07+EPS -> Yb bf16).
// Per K-tile: {8 ds_read | stage(t+2) -> barrier -> 16 MFMA -> vmcnt(3) -> bar}.
// vmcnt never 0 mid-loop. Swizzle (both sides): 16B chunk c = pc ^ ((row>>1)&3).
#define FENCE asm volatile("" ::: "memory")
__device__ __forceinline__ void barx() { FENCE; __builtin_amdgcn_s_barrier(); FENCE; }

__global__ __launch_bounds__(512, 4) void gemm8(const unsigned short* __restrict__ V,
                                                const unsigned short* __restrict__ SW,
                                                float* __restrict__ OUT,
                                                unsigned short* __restrict__ Yb,
                                                int boff) {
  __shared__ __align__(16) unsigned short As[3][128 * 32];
  __shared__ __align__(16) unsigned short Bs[3][256 * 32];
  const int id = blockIdx.x + boff;
  const bool att = id < 256;
  const int r = att ? id : id - 256;
  const int b = r & 7;                 // batch -> XCD affinity
  const int tile = r >> 3;             // 0..31
  const int m0 = (tile & 7) * 128;
  const int n0 = (tile >> 3) * 256;
  const int K = att ? 2048 : 1024;
  const int NN = 1024;
  const unsigned short* Ab = att ? (V + (size_t)b * NN * 2048) : (SW + (size_t)b * NN * NN);

  const int tid = threadIdx.x;
  const int lane = tid & 63;
  const int wid = tid >> 6;            // 8 waves: 2 (M) x 4 (N)
  const int wm = (wid >> 2) * 64;      // 0,64
  const int wn = (wid & 3) * 64;       // 0..192
  const int fr = lane & 15;
  const int fc = lane >> 4;
  const int rsw = (fc ^ ((fr >> 1) & 3)) << 3;   // lane-constant read swizzle

  f32x4 acc[4][4] = {};
  bf16x8 af[4], bf[4];

  auto stage = [&](int sb, int kt) {   // 3 x global_load_lds (A:1, B:2)
    const int k0 = kt << 5;
    {
      const int row = tid >> 2;
      const int c = (tid & 3) ^ ((row >> 1) & 3);
      __builtin_amdgcn_global_load_lds(
          (const AS1 unsigned int*)(Ab + (size_t)(m0 + row) * K + k0 + (c << 3)),
          (AS3 unsigned int*)(&As[sb][tid * 8]), 16, 0, 0);
    }
    #pragma unroll
    for (int e = 0; e < 2; ++e) {
      const int idx = e * 512 + tid;
      const int row = idx >> 2;
      const int c = (idx & 3) ^ ((row >> 1) & 3);
      __builtin_amdgcn_global_load_lds(
          (const AS1 unsigned int*)(Ab + (size_t)(n0 + row) * K + k0 + (c << 3)),
          (AS3 unsigned int*)(&Bs[sb][idx * 8]), 16, 0, 0);
    }
  };

  const int nk = K >> 5;               // 64 (att) / 32 (y)

  stage(0, 0);
  stage(1, 1);
  asm volatile("s_waitcnt vmcnt(3)" ::: "memory");   // tile 0 resident
  barx();

  int rd = 0;
  for (int t = 0; t < nk; ++t) {
    const unsigned short* Ar = As[rd];
    const unsigned short* Br = Bs[rd];
    #pragma unroll
    for (int i = 0; i < 4; ++i)
      af[i] = *(const bf16x8*)(Ar + (wm + i * 16 + fr) * 32 + rsw);
    #pragma unroll
    for (int j = 0; j < 4; ++j)
      bf[j] = *(const bf16x8*)(Br + (wn + j * 16 + fr) * 32 + rsw);

    if (t + 2 < nk) {
      int st = rd + 2; if (st >= 3) st -= 3;   // == (t+2)%3; last read at t-1
      stage(st, t + 2);
    }
    barx();
    asm volatile("s_waitcnt lgkmcnt(0)" ::: "memory");
    __builtin_amdgcn_s_setprio(1);
    #pragma unroll
    for (int i = 0; i < 4; ++i)
      #pragma unroll
      for (int j = 0; j < 4; ++j)
        acc[i][j] = __builtin_amdgcn_mfma_f32_16x16x32_bf16(af[i], bf[j], acc[i][j], 0, 0, 0);
    __builtin_amdgcn_s_setprio(0);
    if (t + 2 < nk)      { asm volatile("s_waitcnt vmcnt(3)" ::: "memory"); }  // t+1 resident
    else if (t + 1 < nk) { asm volatile("s_waitcnt vmcnt(0)" ::: "memory"); }
    barx();
    rd = (rd + 1 == 3) ? 0 : rd + 1;
  }

  if (att) {
    float* Cb = OUT + (size_t)b * NN * NN;
    #pragma unroll
    for (int i = 0; i < 4; ++i)
      #pragma unroll
      for (int rr = 0; rr < 4; ++rr) {
        const int row = m0 + wm + i * 16 + fc * 4 + rr;
        #pragma unroll
        for (int j = 0; j < 4; ++j) {
          const int col = n0 + wn + j * 16 + fr;
          Cb[(size_t)row * NN + col] = fmaxf(acc[i][j][rr] * (1.0f / 16.0f), 0.0f);
        }
      }
  } else {
    unsigned short* Cb = Yb + (size_t)b * NN * NN;
    #pragma unroll
    for (int i = 0; i < 4; ++i)
      #pragma unroll
      for (int rr = 0; rr < 4; ++rr) {
        const int row = m0 + wm + i * 16 + fc * 4 + rr;
        #pragma unroll
        for (int j = 0; j < 4; ++j) {
          const int col = n0 + wn + j * 16 + fr;
          Cb[(size_t)row * NN + col] = f2b(acc[i][j][rr] * (1.4f / 20.0f) + EPSV);
        }
      }
  }
}

// ---------------- finisher: wave-per-row, no syncthreads ---------------------
// grid = BN/4 blocks x 256 thr; each wave owns one (b,n) row of 1024.
__global__ __launch_bounds__(256) void finkern(const unsigned short* __restrict__ Yb,
                                               const unsigned short* __restrict__ SW,
                                               float* __restrict__ OUT) {
  const int row = blockIdx.x * 4 + (threadIdx.x >> 6);   // 0..BN-1
  const int lane = threadIdx.x & 63;
  const unsigned short* y = Yb + (size_t)row * 1024;
  const unsigned short* sw = SW + (size_t)row * 1024;
  float* o = OUT + (size_t)row * 1024;

  float yv[16];
  float ss = 0.0f;
  #pragma unroll
  for (int ch = 0; ch < 4; ++ch) {
    const u16x4 yr = *(const u16x4*)(y + ch * 256 + lane * 4);
    #pragma unroll
    for (int i = 0; i < 4; ++i) {
      yv[ch * 4 + i] = b2f(yr[i]);
      ss += yv[ch * 4 + i] * yv[ch * 4 + i];
    }
  }
  #pragma unroll
  for (int off = 32; off; off >>= 1) ss += __shfl_xor(ss, off);
  const float invy = 1.0f / fmaxf(sqrtf(ss), 1e-12f);

  float tv[16];
  float st = 0.0f;
  #pragma unroll
  for (int ch = 0; ch < 4; ++ch) {
    const u16x4 sr = *(const u16x4*)(sw + ch * 256 + lane * 4);
    #pragma unroll
    for (int i = 0; i < 4; ++i) {
      const float x = fabsf(0.5f * b2f(sr[i]) + sqrtf(yv[ch * 4 + i] * invy)) + EPSV;
      tv[ch * 4 + i] = x;
      st += x * x;
    }
  }
  #pragma unroll
  for (int off = 32; off; off >>= 1) st += __shfl_xor(st, off);
  const float invt = 1.0f / fmaxf(sqrtf(st), 1e-12f);

  #pragma unroll
  for (int ch = 0; ch < 4; ++ch) {
    f32x4 ov = *(f32x4*)(o + ch * 256 + lane * 4);
    #pragma unroll
    for (int i = 0; i < 4; ++i) ov[i] *= tv[ch * 4 + i] * invt;
    *(f32x4*)(o + ch * 256 + lane * 4) = ov;
  }
}

extern "C" void kernel_launch(void* const* d_in, const int* in_sizes, int n_in,
                              void* d_out, int out_size, void* d_ws, size_t ws_size,
                              hipStream_t stream) {
  const float* ctx        = (const float*)d_in[0];
  const float* acc_u      = (const float*)d_in[1];
  const float* acc_v      = (const float*)d_in[2];
  const float* uv_angle   = (const float*)d_in[3];
  const float* uv_angleACC= (const float*)d_in[4];
  const float* speed      = (const float*)d_in[5];
  // d_in[6] = isPhy (unused by the reference computation)
  const float* dist       = (const float*)d_in[7];
  const float* angle      = (const float*)d_in[8];
  const float* wt         = (const float*)d_in[9];

  const int B = 8, N = 1024, P = 16;
  const int K1 = P * 128;  // 2048
  const int BN = B * N;    // 8192 rows

  const size_t szV  = (size_t)BN * K1 * 2;   // 33.5 MB bf16
  const size_t szSW = (size_t)BN * N * 2;    // 16.8 MB bf16
  const size_t szYb = (size_t)BN * N * 2;    // 16.8 MB bf16
  const size_t szT  = (size_t)N * N * 4;     // 4.2 MB per table

  unsigned short* V  = (unsigned short*)d_ws;
  unsigned short* SW = (unsigned short*)((char*)d_ws + szV);
  float* out = (float*)d_out;

  if (ws_size >= szV + szSW + szYb) {
    // tables alias the Yb region (dead before gemm8 writes Yb):
    // region3 = [szV+szSW, szV+szSW+16.8MB): CT (4.2MB) | ST (4.2MB)
    char* region3 = (char*)d_ws + szV + szSW;
    float* CT = (float*)region3;
    float* ST = (float*)(region3 + szT);
    unsigned short* Yp = (unsigned short*)region3;

    tabkern<<<dim3(N * N / 1024), dim3(256), 0, stream>>>(angle, dist, CT, ST);
    prep<<<dim3(2 * BN), dim3(256), 0, stream>>>(ctx, wt, speed, uv_angle, acc_u,
                                                 acc_v, uv_angleACC, CT, ST, dist,
                                                 V, SW, BN, N);
    gemm8<<<dim3(512), dim3(512), 0, stream>>>(V, SW, out, Yp, 0);
    finkern<<<dim3(BN / 4), dim3(256), 0, stream>>>(Yp, SW, out);
  } else {
    // split fallback: tables after SW; Yb aliases V (consumed by att pass)
    char* tabs = (char*)d_ws + szV + szSW;
    float* CT = (float*)tabs;
    float* ST = (float*)(tabs + szT);
    unsigned short* Yp = (unsigned short*)d_ws;

    tabkern<<<dim3(N * N / 1024), dim3(256), 0, stream>>>(angle, dist, CT, ST);
    prep<<<dim3(2 * BN), dim3(256), 0, stream>>>(ctx, wt, speed, uv_angle, acc_u,
                                                 acc_v, uv_angleACC, CT, ST, dist,
                                                 V, SW, BN, N);
    gemm8<<<dim3(256), dim3(512), 0, stream>>>(V, SW, out, Yp, 0);
    gemm8<<<dim3(256), dim3(512), 0, stream>>>(V, SW, out, Yp, 256);
    finkern<<<dim3(BN / 4), dim3(256), 0, stream>>>(Yp, SW, out);
  }
}

// Round 10
// 169.712 us; speedup vs baseline: 1.0848x; 1.0211x over previous
//
#include <hip/hip_runtime.h>
#include <hip/hip_bf16.h>
#include <math.h>

#define EPSV 1e-5f
#define AS1 __attribute__((address_space(1)))
#define AS3 __attribute__((address_space(3)))

typedef __attribute__((ext_vector_type(4))) float f32x4;
typedef __attribute__((ext_vector_type(8))) short bf16x8;
typedef __attribute__((ext_vector_type(4))) unsigned short u16x4;

__device__ __forceinline__ unsigned short f2b(float x) {
  union { float f; unsigned int u; } v; v.f = x;
  unsigned int r = v.u + 0x7FFFu + ((v.u >> 16) & 1u);
  return (unsigned short)(r >> 16);
}
__device__ __forceinline__ float b2f(unsigned short h) {
  union { float f; unsigned int u; } v; v.u = ((unsigned int)h) << 16;
  return v.f;
}

// block = 256 threads = 4 waves; sbuf must have 4 floats
__device__ __forceinline__ float block_reduce_sum(float v, float* sbuf) {
  #pragma unroll
  for (int off = 32; off; off >>= 1) v += __shfl_xor(v, off);
  __syncthreads();
  if ((threadIdx.x & 63) == 0) sbuf[threadIdx.x >> 6] = v;
  __syncthreads();
  return sbuf[0] + sbuf[1] + sbuf[2] + sbuf[3];
}

// ---------------- prep: one block per bn row; V phase then SW phase ----------
// V[bn, p*128+d] = l2norm_d(context*w_p) bf16.
// SW[bn, m] = l2norm_m( sp*|cos(angle-ua) (+ diag 0.5*ta)| / (dist+EPS) ) bf16.
__global__ __launch_bounds__(256) void prep(const float* __restrict__ ctx,
                                            const float* __restrict__ wt,
                                            const float* __restrict__ speed,
                                            const float* __restrict__ uva,
                                            const float* __restrict__ accu,
                                            const float* __restrict__ accv,
                                            const float* __restrict__ uvaACC,
                                            const float* __restrict__ angle,
                                            const float* __restrict__ dist,
                                            unsigned short* __restrict__ V,
                                            unsigned short* __restrict__ SW,
                                            int N) {
  __shared__ float sbuf[4];
  const int bn = blockIdx.x;
  const int tid = threadIdx.x;

  // ---- phase A: V (4 waves x 4 p each; 16-lane group per p, 8 d per lane)
  {
    const int w = tid >> 6;
    const int lane = tid & 63;
    const int p = w * 4 + (lane >> 4);
    const int dl = (lane & 15) * 8;
    const float* c = ctx + (size_t)bn * 128;
    const f32x4 ca = *(const f32x4*)(c + dl);
    const f32x4 cb = *(const f32x4*)(c + dl + 4);
    const f32x4 wa = *(const f32x4*)(wt + p * 128 + dl);
    const f32x4 wb = *(const f32x4*)(wt + p * 128 + dl + 4);
    float a[8];
    float ss = 0.0f;
    #pragma unroll
    for (int i = 0; i < 4; ++i) {
      a[i] = ca[i] * wa[i];
      a[4 + i] = cb[i] * wb[i];
      ss += a[i] * a[i] + a[4 + i] * a[4 + i];
    }
    ss += __shfl_xor(ss, 1);
    ss += __shfl_xor(ss, 2);
    ss += __shfl_xor(ss, 4);
    ss += __shfl_xor(ss, 8);
    const float inv = 1.0f / fmaxf(sqrtf(ss), 1e-12f);
    bf16x8 o;
    #pragma unroll
    for (int i = 0; i < 8; ++i) o[i] = (short)f2b(a[i] * inv);
    *(bf16x8*)(V + (size_t)bn * 2048 + p * 128 + dl) = o;
  }

  // ---- phase B: SW row (4 consecutive m per thread)
  {
    const int n = bn & (N - 1);
    const float ua = uva[bn];
    const float sp = fabsf(speed[bn]);
    const float au = accu[bn], av = accv[bn];
    const float ta = sqrtf(au * au + av * av + EPSV) * fabsf(cosf(uvaACC[bn] - ua));
    const f32x4 an = *(const f32x4*)(angle + (size_t)n * N + 4 * tid);
    const f32x4 dv = *(const f32x4*)(dist + (size_t)n * N + 4 * tid);
    float v[4];
    float ss = 0.0f;
    #pragma unroll
    for (int i = 0; i < 4; ++i) {
      float cv = cosf(an[i] - ua);
      if (4 * tid + i == n) cv += 0.5f * ta;   // sigma * acc_part inside the abs
      v[i] = sp * fabsf(cv) / (dv[i] + EPSV);
      ss += v[i] * v[i];
    }
    ss = block_reduce_sum(ss, sbuf);
    const float inv = 1.0f / fmaxf(sqrtf(ss), 1e-12f);
    u16x4 o;
    #pragma unroll
    for (int i = 0; i < 4; ++i) o[i] = f2b(v[i] * inv);
    *(u16x4*)(SW + (size_t)bn * N + 4 * tid) = o;
  }
}

// ---------------- 8-wave 128x256 GEMM, single-barrier K-loop -----------------
// id<256: att tile (V, K=2048, relu/16 -> ATT bf16 or OUT f32).
// id>=256: y tile (SW, K=1024, *0.07+EPS -> Yb bf16).
// Per K-tile: {stage(t+2) | ds_read(rd) -> MFMA (compiler lgkmcnt) ->
// vmcnt(3) -> s_barrier}. vmcnt never 0 mid-loop; 3-buf ring; both-sides
// chunk swizzle c = pc ^ ((row>>1)&3) (0 conflicts, proven R3-R9).
#define FENCE asm volatile("" ::: "memory")
__device__ __forceinline__ void barx() { FENCE; __builtin_amdgcn_s_barrier(); FENCE; }

template <bool ATTB>
__global__ __launch_bounds__(512, 4) void gemm8(const unsigned short* __restrict__ V,
                                                const unsigned short* __restrict__ SW,
                                                float* __restrict__ OUT,
                                                unsigned short* __restrict__ Yb,
                                                unsigned short* __restrict__ ATT,
                                                int boff) {
  __shared__ __align__(16) unsigned short As[3][128 * 32];
  __shared__ __align__(16) unsigned short Bs[3][256 * 32];
  const int id = blockIdx.x + boff;
  const bool att = id < 256;
  const int r = att ? id : id - 256;
  const int b = r & 7;                 // batch -> XCD affinity
  const int tile = r >> 3;             // 0..31
  const int m0 = (tile & 7) * 128;
  const int n0 = (tile >> 3) * 256;
  const int K = att ? 2048 : 1024;
  const int NN = 1024;
  const unsigned short* Ab = att ? (V + (size_t)b * NN * 2048) : (SW + (size_t)b * NN * NN);

  const int tid = threadIdx.x;
  const int lane = tid & 63;
  const int wid = tid >> 6;            // 8 waves: 2 (M) x 4 (N)
  const int wm = (wid >> 2) * 64;      // 0,64
  const int wn = (wid & 3) * 64;       // 0..192
  const int fr = lane & 15;
  const int fc = lane >> 4;
  const int rsw = (fc ^ ((fr >> 1) & 3)) << 3;   // lane-constant read swizzle

  f32x4 acc[4][4] = {};
  bf16x8 af[4], bf[4];

  auto stage = [&](int sb, int kt) {   // 3 x global_load_lds / thread (A:1, B:2)
    const int k0 = kt << 5;
    {
      const int row = tid >> 2;
      const int c = (tid & 3) ^ ((row >> 1) & 3);
      __builtin_amdgcn_global_load_lds(
          (const AS1 unsigned int*)(Ab + (size_t)(m0 + row) * K + k0 + (c << 3)),
          (AS3 unsigned int*)(&As[sb][tid * 8]), 16, 0, 0);
    }
    #pragma unroll
    for (int e = 0; e < 2; ++e) {
      const int idx = e * 512 + tid;
      const int row = idx >> 2;
      const int c = (idx & 3) ^ ((row >> 1) & 3);
      __builtin_amdgcn_global_load_lds(
          (const AS1 unsigned int*)(Ab + (size_t)(n0 + row) * K + k0 + (c << 3)),
          (AS3 unsigned int*)(&Bs[sb][idx * 8]), 16, 0, 0);
    }
  };

  const int nk = K >> 5;               // 64 (att) / 32 (y)

  stage(0, 0);
  stage(1, 1);
  asm volatile("s_waitcnt vmcnt(3)" ::: "memory");   // tile 0 resident
  barx();

  int rd = 0;
  for (int t = 0; t < nk; ++t) {
    if (t + 2 < nk) {
      int st = rd + 2; if (st >= 3) st -= 3;   // buf last read at t-1 -> safe
      stage(st, t + 2);
    }
    const unsigned short* Ar = As[rd];
    const unsigned short* Br = Bs[rd];
    #pragma unroll
    for (int i = 0; i < 4; ++i)
      af[i] = *(const bf16x8*)(Ar + (wm + i * 16 + fr) * 32 + rsw);
    #pragma unroll
    for (int j = 0; j < 4; ++j)
      bf[j] = *(const bf16x8*)(Br + (wn + j * 16 + fr) * 32 + rsw);
    __builtin_amdgcn_s_setprio(1);
    #pragma unroll
    for (int i = 0; i < 4; ++i)
      #pragma unroll
      for (int j = 0; j < 4; ++j)
        acc[i][j] = __builtin_amdgcn_mfma_f32_16x16x32_bf16(af[i], bf[j], acc[i][j], 0, 0, 0);
    __builtin_amdgcn_s_setprio(0);
    if (t + 2 < nk)      { asm volatile("s_waitcnt vmcnt(3)" ::: "memory"); }  // t+1 resident
    else if (t + 1 < nk) { asm volatile("s_waitcnt vmcnt(0)" ::: "memory"); }
    barx();
    rd = (rd + 1 == 3) ? 0 : rd + 1;
  }

  if (att) {
    if (ATTB) {
      unsigned short* Cb = ATT + (size_t)b * NN * NN;
      #pragma unroll
      for (int i = 0; i < 4; ++i)
        #pragma unroll
        for (int rr = 0; rr < 4; ++rr) {
          const int row = m0 + wm + i * 16 + fc * 4 + rr;
          #pragma unroll
          for (int j = 0; j < 4; ++j) {
            const int col = n0 + wn + j * 16 + fr;
            Cb[(size_t)row * NN + col] = f2b(fmaxf(acc[i][j][rr] * (1.0f / 16.0f), 0.0f));
          }
        }
    } else {
      float* Cb = OUT + (size_t)b * NN * NN;
      #pragma unroll
      for (int i = 0; i < 4; ++i)
        #pragma unroll
        for (int rr = 0; rr < 4; ++rr) {
          const int row = m0 + wm + i * 16 + fc * 4 + rr;
          #pragma unroll
          for (int j = 0; j < 4; ++j) {
            const int col = n0 + wn + j * 16 + fr;
            Cb[(size_t)row * NN + col] = fmaxf(acc[i][j][rr] * (1.0f / 16.0f), 0.0f);
          }
        }
    }
  } else {
    unsigned short* Cb = Yb + (size_t)b * NN * NN;
    #pragma unroll
    for (int i = 0; i < 4; ++i)
      #pragma unroll
      for (int rr = 0; rr < 4; ++rr) {
        const int row = m0 + wm + i * 16 + fc * 4 + rr;
        #pragma unroll
        for (int j = 0; j < 4; ++j) {
          const int col = n0 + wn + j * 16 + fr;
          Cb[(size_t)row * NN + col] = f2b(acc[i][j][rr] * (1.4f / 20.0f) + EPSV);
        }
      }
  }
}

// ---------------- finisher: wave-per-row -------------------------------------
// ATTB=1: OUT = b2f(ATT) * t/||t|| (write-only). ATTB=0: OUT *= t/||t|| (RMW).
template <bool ATTB>
__global__ __launch_bounds__(256) void finkern(const unsigned short* __restrict__ Yb,
                                               const unsigned short* __restrict__ SW,
                                               const unsigned short* __restrict__ ATT,
                                               float* __restrict__ OUT) {
  const int row = blockIdx.x * 4 + (threadIdx.x >> 6);   // 0..BN-1
  const int lane = threadIdx.x & 63;
  const unsigned short* y = Yb + (size_t)row * 1024;
  const unsigned short* sw = SW + (size_t)row * 1024;
  float* o = OUT + (size_t)row * 1024;

  float yv[16];
  float ss = 0.0f;
  #pragma unroll
  for (int ch = 0; ch < 4; ++ch) {
    const u16x4 yr = *(const u16x4*)(y + ch * 256 + lane * 4);
    #pragma unroll
    for (int i = 0; i < 4; ++i) {
      yv[ch * 4 + i] = b2f(yr[i]);
      ss += yv[ch * 4 + i] * yv[ch * 4 + i];
    }
  }
  #pragma unroll
  for (int off = 32; off; off >>= 1) ss += __shfl_xor(ss, off);
  const float invy = 1.0f / fmaxf(sqrtf(ss), 1e-12f);

  float tv[16];
  float st = 0.0f;
  #pragma unroll
  for (int ch = 0; ch < 4; ++ch) {
    const u16x4 sr = *(const u16x4*)(sw + ch * 256 + lane * 4);
    #pragma unroll
    for (int i = 0; i < 4; ++i) {
      const float x = fabsf(0.5f * b2f(sr[i]) + sqrtf(yv[ch * 4 + i] * invy)) + EPSV;
      tv[ch * 4 + i] = x;
      st += x * x;
    }
  }
  #pragma unroll
  for (int off = 32; off; off >>= 1) st += __shfl_xor(st, off);
  const float invt = 1.0f / fmaxf(sqrtf(st), 1e-12f);

  if (ATTB) {
    const unsigned short* at = ATT + (size_t)row * 1024;
    #pragma unroll
    for (int ch = 0; ch < 4; ++ch) {
      const u16x4 ar = *(const u16x4*)(at + ch * 256 + lane * 4);
      f32x4 ov;
      #pragma unroll
      for (int i = 0; i < 4; ++i) ov[i] = b2f(ar[i]) * (tv[ch * 4 + i] * invt);
      *(f32x4*)(o + ch * 256 + lane * 4) = ov;
    }
  } else {
    #pragma unroll
    for (int ch = 0; ch < 4; ++ch) {
      f32x4 ov = *(f32x4*)(o + ch * 256 + lane * 4);
      #pragma unroll
      for (int i = 0; i < 4; ++i) ov[i] *= tv[ch * 4 + i] * invt;
      *(f32x4*)(o + ch * 256 + lane * 4) = ov;
    }
  }
}

extern "C" void kernel_launch(void* const* d_in, const int* in_sizes, int n_in,
                              void* d_out, int out_size, void* d_ws, size_t ws_size,
                              hipStream_t stream) {
  const float* ctx        = (const float*)d_in[0];
  const float* acc_u      = (const float*)d_in[1];
  const float* acc_v      = (const float*)d_in[2];
  const float* uv_angle   = (const float*)d_in[3];
  const float* uv_angleACC= (const float*)d_in[4];
  const float* speed      = (const float*)d_in[5];
  // d_in[6] = isPhy (unused by the reference computation)
  const float* dist       = (const float*)d_in[7];
  const float* angle      = (const float*)d_in[8];
  const float* wt         = (const float*)d_in[9];

  const int B = 8, N = 1024, P = 16;
  const int K1 = P * 128;  // 2048
  const int BN = B * N;    // 8192 rows

  const size_t szV  = (size_t)BN * K1 * 2;   // 33.5 MB bf16
  const size_t szSW = (size_t)BN * N * 2;    // 16.8 MB bf16
  const size_t szYb = (size_t)BN * N * 2;    // 16.8 MB bf16
  const size_t szA  = (size_t)BN * N * 2;    // 16.8 MB bf16

  unsigned short* V  = (unsigned short*)d_ws;
  unsigned short* SW = (unsigned short*)((char*)d_ws + szV);
  float* out = (float*)d_out;

  prep<<<dim3(BN), dim3(256), 0, stream>>>(ctx, wt, speed, uv_angle, acc_u,
                                           acc_v, uv_angleACC, angle, dist,
                                           V, SW, N);

  if (ws_size >= szV + szSW + szYb + szA) {
    // best path: att stored bf16 in ws; finkern write-only on OUT
    unsigned short* Yp = (unsigned short*)((char*)d_ws + szV + szSW);
    unsigned short* At = (unsigned short*)((char*)d_ws + szV + szSW + szYb);
    gemm8<true><<<dim3(512), dim3(512), 0, stream>>>(V, SW, out, Yp, At, 0);
    finkern<true><<<dim3(BN / 4), dim3(256), 0, stream>>>(Yp, SW, At, out);
  } else if (ws_size >= szV + szSW + szYb) {
    // att f32 direct to OUT; finkern RMW
    unsigned short* Yp = (unsigned short*)((char*)d_ws + szV + szSW);
    gemm8<false><<<dim3(512), dim3(512), 0, stream>>>(V, SW, out, Yp, nullptr, 0);
    finkern<false><<<dim3(BN / 4), dim3(256), 0, stream>>>(Yp, SW, nullptr, out);
  } else {
    // split fallback: att pass first (consumes V), then y pass with Yb alias V
    unsigned short* Yp = (unsigned short*)d_ws;
    gemm8<false><<<dim3(256), dim3(512), 0, stream>>>(V, SW, out, Yp, nullptr, 0);
    gemm8<false><<<dim3(256), dim3(512), 0, stream>>>(V, SW, out, Yp, nullptr, 256);
    finkern<false><<<dim3(BN / 4), dim3(256), 0, stream>>>(Yp, SW, nullptr, out);
  }
}

// Round 11
// 167.942 us; speedup vs baseline: 1.0962x; 1.0105x over previous
//
#include <hip/hip_runtime.h>
#include <hip/hip_bf16.h>
#include <math.h>

#define EPSV 1e-5f
#define AS1 __attribute__((address_space(1)))
#define AS3 __attribute__((address_space(3)))

typedef __attribute__((ext_vector_type(4))) float f32x4;
typedef __attribute__((ext_vector_type(8))) short bf16x8;
typedef __attribute__((ext_vector_type(4))) unsigned short u16x4;

__device__ __forceinline__ unsigned short f2b(float x) {
  union { float f; unsigned int u; } v; v.f = x;
  unsigned int r = v.u + 0x7FFFu + ((v.u >> 16) & 1u);
  return (unsigned short)(r >> 16);
}
__device__ __forceinline__ float b2f(unsigned short h) {
  union { float f; unsigned int u; } v; v.u = ((unsigned int)h) << 16;
  return v.f;
}

// block = 256 threads = 4 waves; sbuf must have 4 floats
__device__ __forceinline__ float block_reduce_sum(float v, float* sbuf) {
  #pragma unroll
  for (int off = 32; off; off >>= 1) v += __shfl_xor(v, off);
  __syncthreads();
  if ((threadIdx.x & 63) == 0) sbuf[threadIdx.x >> 6] = v;
  __syncthreads();
  return sbuf[0] + sbuf[1] + sbuf[2] + sbuf[3];
}

// ---------------- prep: one block per bn row; V phase then SW phase ----------
__global__ __launch_bounds__(256) void prep(const float* __restrict__ ctx,
                                            const float* __restrict__ wt,
                                            const float* __restrict__ speed,
                                            const float* __restrict__ uva,
                                            const float* __restrict__ accu,
                                            const float* __restrict__ accv,
                                            const float* __restrict__ uvaACC,
                                            const float* __restrict__ angle,
                                            const float* __restrict__ dist,
                                            unsigned short* __restrict__ V,
                                            unsigned short* __restrict__ SW,
                                            int N) {
  __shared__ float sbuf[4];
  const int bn = blockIdx.x;
  const int tid = threadIdx.x;

  // ---- phase A: V (4 waves x 4 p each; 16-lane group per p, 8 d per lane)
  {
    const int w = tid >> 6;
    const int lane = tid & 63;
    const int p = w * 4 + (lane >> 4);
    const int dl = (lane & 15) * 8;
    const float* c = ctx + (size_t)bn * 128;
    const f32x4 ca = *(const f32x4*)(c + dl);
    const f32x4 cb = *(const f32x4*)(c + dl + 4);
    const f32x4 wa = *(const f32x4*)(wt + p * 128 + dl);
    const f32x4 wb = *(const f32x4*)(wt + p * 128 + dl + 4);
    float a[8];
    float ss = 0.0f;
    #pragma unroll
    for (int i = 0; i < 4; ++i) {
      a[i] = ca[i] * wa[i];
      a[4 + i] = cb[i] * wb[i];
      ss += a[i] * a[i] + a[4 + i] * a[4 + i];
    }
    ss += __shfl_xor(ss, 1);
    ss += __shfl_xor(ss, 2);
    ss += __shfl_xor(ss, 4);
    ss += __shfl_xor(ss, 8);
    const float inv = 1.0f / fmaxf(sqrtf(ss), 1e-12f);
    bf16x8 o;
    #pragma unroll
    for (int i = 0; i < 8; ++i) o[i] = (short)f2b(a[i] * inv);
    *(bf16x8*)(V + (size_t)bn * 2048 + p * 128 + dl) = o;
  }

  // ---- phase B: SW row (4 consecutive m per thread)
  {
    const int n = bn & (N - 1);
    const float ua = uva[bn];
    const float sp = fabsf(speed[bn]);
    const float au = accu[bn], av = accv[bn];
    const float ta = sqrtf(au * au + av * av + EPSV) * fabsf(cosf(uvaACC[bn] - ua));
    const f32x4 an = *(const f32x4*)(angle + (size_t)n * N + 4 * tid);
    const f32x4 dv = *(const f32x4*)(dist + (size_t)n * N + 4 * tid);
    float v[4];
    float ss = 0.0f;
    #pragma unroll
    for (int i = 0; i < 4; ++i) {
      float cv = cosf(an[i] - ua);
      if (4 * tid + i == n) cv += 0.5f * ta;   // sigma * acc_part inside the abs
      v[i] = sp * fabsf(cv) / (dv[i] + EPSV);
      ss += v[i] * v[i];
    }
    ss = block_reduce_sum(ss, sbuf);
    const float inv = 1.0f / fmaxf(sqrtf(ss), 1e-12f);
    u16x4 o;
    #pragma unroll
    for (int i = 0; i < 4; ++i) o[i] = f2b(v[i] * inv);
    *(u16x4*)(SW + (size_t)bn * N + 4 * tid) = o;
  }
}

// ---------------- triangle Gram GEMM -----------------------------------------
// Both GEMMs are A·Aᵀ (symmetric): compute only the 36 upper-triangle 128x128
// tiles per batch; mirror off-diagonal tiles via transposed u16x4 stores
// (lane's 4 acc rr-values are consecutive along the transposed row).
// mode 0: grid 576, id&1 selects {att,y}; mode 1: att only (288); mode 2: y (288).
// K-loop: R9-proven two-barrier, 3-buf ring, counted vmcnt(4), both-sides
// chunk swizzle c = pc ^ ((row>>1)&3) (0 conflicts, proven R3-R10).
#define FENCE asm volatile("" ::: "memory")
__device__ __forceinline__ void barx() { FENCE; __builtin_amdgcn_s_barrier(); FENCE; }

template <bool ATTB>
__global__ __launch_bounds__(256, 3) void gemmT(const unsigned short* __restrict__ V,
                                                const unsigned short* __restrict__ SW,
                                                float* __restrict__ OUT,
                                                unsigned short* __restrict__ Yb,
                                                unsigned short* __restrict__ ATT,
                                                int mode) {
  __shared__ __align__(16) unsigned short As[3][128 * 32];
  __shared__ __align__(16) unsigned short Bs[3][128 * 32];
  const int id = blockIdx.x;
  const bool isatt = (mode == 0) ? ((id & 1) == 0) : (mode == 1);
  const int r = (mode == 0) ? (id >> 1) : id;
  const int b = r & 7;                 // batch -> XCD spread
  int t = r >> 3;                      // 0..35 upper-triangle tile
  int ti = 0;
  while (t >= 8 - ti) { t -= 8 - ti; ++ti; }
  const int tj = ti + t;               // ti <= tj < 8
  const int m0 = ti * 128;
  const int n0 = tj * 128;
  const int K = isatt ? 2048 : 1024;
  const int NN = 1024;
  const unsigned short* Ab = isatt ? (V + (size_t)b * NN * 2048)
                                   : (SW + (size_t)b * NN * NN);

  const int tid = threadIdx.x;
  const int lane = tid & 63;
  const int wid = tid >> 6;            // 4 waves: 2 (M) x 2 (N)
  const int wm = (wid >> 1) * 64;
  const int wn = (wid & 1) * 64;
  const int fr = lane & 15;
  const int fc = lane >> 4;
  const int rsw = (fc ^ ((fr >> 1) & 3)) << 3;   // lane-constant read swizzle

  f32x4 acc[4][4] = {};
  bf16x8 af[4], bf[4];

  auto stage = [&](int sb, int kt) {   // 4 loads/thread: A x2, B x2
    const int k0 = kt << 5;
    #pragma unroll
    for (int e = 0; e < 2; ++e) {
      const int idx = e * 256 + tid;   // 16B chunk id, 0..511
      const int row = idx >> 2;
      const int c = (idx & 3) ^ ((row >> 1) & 3);
      __builtin_amdgcn_global_load_lds(
          (const AS1 unsigned int*)(Ab + (size_t)(m0 + row) * K + k0 + (c << 3)),
          (AS3 unsigned int*)(&As[sb][idx * 8]), 16, 0, 0);
      __builtin_amdgcn_global_load_lds(
          (const AS1 unsigned int*)(Ab + (size_t)(n0 + row) * K + k0 + (c << 3)),
          (AS3 unsigned int*)(&Bs[sb][idx * 8]), 16, 0, 0);
    }
  };

  const int nk = K >> 5;               // 64 (att) / 32 (y)

  stage(0, 0);
  stage(1, 1);
  asm volatile("s_waitcnt vmcnt(4)" ::: "memory");   // tile 0 resident
  barx();

  int rd = 0;
  for (int kt = 0; kt < nk; ++kt) {
    const unsigned short* Ar = As[rd];
    const unsigned short* Br = Bs[rd];
    #pragma unroll
    for (int i = 0; i < 4; ++i)
      af[i] = *(const bf16x8*)(Ar + (wm + i * 16 + fr) * 32 + rsw);
    #pragma unroll
    for (int j = 0; j < 4; ++j)
      bf[j] = *(const bf16x8*)(Br + (wn + j * 16 + fr) * 32 + rsw);

    if (kt + 2 < nk) {
      int st = rd + 2; if (st >= 3) st -= 3;   // buf last read at kt-1 -> safe
      stage(st, kt + 2);
    }
    barx();
    asm volatile("s_waitcnt lgkmcnt(0)" ::: "memory");
    __builtin_amdgcn_s_setprio(1);
    #pragma unroll
    for (int i = 0; i < 4; ++i)
      #pragma unroll
      for (int j = 0; j < 4; ++j)
        acc[i][j] = __builtin_amdgcn_mfma_f32_16x16x32_bf16(af[i], bf[j], acc[i][j], 0, 0, 0);
    __builtin_amdgcn_s_setprio(0);
    if (kt + 2 < nk)      { asm volatile("s_waitcnt vmcnt(4)" ::: "memory"); }  // kt+1 resident
    else if (kt + 1 < nk) { asm volatile("s_waitcnt vmcnt(0)" ::: "memory"); }
    barx();
    rd = (rd + 1 == 3) ? 0 : rd + 1;
  }

  const bool mirror = (ti != tj);
  if (isatt && !ATTB) {
    // fallback: f32 att direct to OUT (+ transposed f32x4 mirror)
    float* Cb = OUT + (size_t)b * NN * NN;
    #pragma unroll
    for (int i = 0; i < 4; ++i)
      #pragma unroll
      for (int j = 0; j < 4; ++j) {
        const int col = n0 + wn + j * 16 + fr;
        const int rowb = m0 + wm + i * 16 + fc * 4;
        f32x4 tv;
        #pragma unroll
        for (int rr = 0; rr < 4; ++rr) {
          const float v = fmaxf(acc[i][j][rr] * (1.0f / 16.0f), 0.0f);
          Cb[(size_t)(rowb + rr) * NN + col] = v;
          tv[rr] = v;
        }
        if (mirror) *(f32x4*)(Cb + (size_t)col * NN + rowb) = tv;
      }
  } else {
    // bf16 output (ATT for att, Yb for y) + transposed u16x4 mirror
    unsigned short* Cb = (isatt ? ATT : Yb) + (size_t)b * NN * NN;
    const float scale = isatt ? (1.0f / 16.0f) : (1.4f / 20.0f);
    #pragma unroll
    for (int i = 0; i < 4; ++i)
      #pragma unroll
      for (int j = 0; j < 4; ++j) {
        const int col = n0 + wn + j * 16 + fr;
        const int rowb = m0 + wm + i * 16 + fc * 4;
        u16x4 tv;
        #pragma unroll
        for (int rr = 0; rr < 4; ++rr) {
          const float v = isatt ? fmaxf(acc[i][j][rr] * scale, 0.0f)
                                : (acc[i][j][rr] * scale + EPSV);
          const unsigned short h = f2b(v);
          Cb[(size_t)(rowb + rr) * NN + col] = h;
          tv[rr] = h;
        }
        if (mirror) *(u16x4*)(Cb + (size_t)col * NN + rowb) = tv;
      }
  }
}

// ---------------- finisher: wave-per-row -------------------------------------
// ATTB=1: OUT = b2f(ATT) * t/||t|| (write-only). ATTB=0: OUT *= t/||t|| (RMW).
template <bool ATTB>
__global__ __launch_bounds__(256) void finkern(const unsigned short* __restrict__ Yb,
                                               const unsigned short* __restrict__ SW,
                                               const unsigned short* __restrict__ ATT,
                                               float* __restrict__ OUT) {
  const int row = blockIdx.x * 4 + (threadIdx.x >> 6);   // 0..BN-1
  const int lane = threadIdx.x & 63;
  const unsigned short* y = Yb + (size_t)row * 1024;
  const unsigned short* sw = SW + (size_t)row * 1024;
  float* o = OUT + (size_t)row * 1024;

  float yv[16];
  float ss = 0.0f;
  #pragma unroll
  for (int ch = 0; ch < 4; ++ch) {
    const u16x4 yr = *(const u16x4*)(y + ch * 256 + lane * 4);
    #pragma unroll
    for (int i = 0; i < 4; ++i) {
      yv[ch * 4 + i] = b2f(yr[i]);
      ss += yv[ch * 4 + i] * yv[ch * 4 + i];
    }
  }
  #pragma unroll
  for (int off = 32; off; off >>= 1) ss += __shfl_xor(ss, off);
  const float invy = 1.0f / fmaxf(sqrtf(ss), 1e-12f);

  float tv[16];
  float st = 0.0f;
  #pragma unroll
  for (int ch = 0; ch < 4; ++ch) {
    const u16x4 sr = *(const u16x4*)(sw + ch * 256 + lane * 4);
    #pragma unroll
    for (int i = 0; i < 4; ++i) {
      const float x = fabsf(0.5f * b2f(sr[i]) + sqrtf(yv[ch * 4 + i] * invy)) + EPSV;
      tv[ch * 4 + i] = x;
      st += x * x;
    }
  }
  #pragma unroll
  for (int off = 32; off; off >>= 1) st += __shfl_xor(st, off);
  const float invt = 1.0f / fmaxf(sqrtf(st), 1e-12f);

  if (ATTB) {
    const unsigned short* at = ATT + (size_t)row * 1024;
    #pragma unroll
    for (int ch = 0; ch < 4; ++ch) {
      const u16x4 ar = *(const u16x4*)(at + ch * 256 + lane * 4);
      f32x4 ov;
      #pragma unroll
      for (int i = 0; i < 4; ++i) ov[i] = b2f(ar[i]) * (tv[ch * 4 + i] * invt);
      *(f32x4*)(o + ch * 256 + lane * 4) = ov;
    }
  } else {
    #pragma unroll
    for (int ch = 0; ch < 4; ++ch) {
      f32x4 ov = *(f32x4*)(o + ch * 256 + lane * 4);
      #pragma unroll
      for (int i = 0; i < 4; ++i) ov[i] *= tv[ch * 4 + i] * invt;
      *(f32x4*)(o + ch * 256 + lane * 4) = ov;
    }
  }
}

extern "C" void kernel_launch(void* const* d_in, const int* in_sizes, int n_in,
                              void* d_out, int out_size, void* d_ws, size_t ws_size,
                              hipStream_t stream) {
  const float* ctx        = (const float*)d_in[0];
  const float* acc_u      = (const float*)d_in[1];
  const float* acc_v      = (const float*)d_in[2];
  const float* uv_angle   = (const float*)d_in[3];
  const float* uv_angleACC= (const float*)d_in[4];
  const float* speed      = (const float*)d_in[5];
  // d_in[6] = isPhy (unused by the reference computation)
  const float* dist       = (const float*)d_in[7];
  const float* angle      = (const float*)d_in[8];
  const float* wt         = (const float*)d_in[9];

  const int B = 8, N = 1024, P = 16;
  const int K1 = P * 128;  // 2048
  const int BN = B * N;    // 8192 rows

  const size_t szV  = (size_t)BN * K1 * 2;   // 33.5 MB bf16
  const size_t szSW = (size_t)BN * N * 2;    // 16.8 MB bf16
  const size_t szYb = (size_t)BN * N * 2;    // 16.8 MB bf16
  const size_t szA  = (size_t)BN * N * 2;    // 16.8 MB bf16

  unsigned short* V  = (unsigned short*)d_ws;
  unsigned short* SW = (unsigned short*)((char*)d_ws + szV);
  float* out = (float*)d_out;

  prep<<<dim3(BN), dim3(256), 0, stream>>>(ctx, wt, speed, uv_angle, acc_u,
                                           acc_v, uv_angleACC, angle, dist,
                                           V, SW, N);

  if (ws_size >= szV + szSW + szYb + szA) {
    // best path: triangle gemm, att bf16 in ws; finkern write-only on OUT
    unsigned short* Yp = (unsigned short*)((char*)d_ws + szV + szSW);
    unsigned short* At = (unsigned short*)((char*)d_ws + szV + szSW + szYb);
    gemmT<true><<<dim3(576), dim3(256), 0, stream>>>(V, SW, out, Yp, At, 0);
    finkern<true><<<dim3(BN / 4), dim3(256), 0, stream>>>(Yp, SW, At, out);
  } else if (ws_size >= szV + szSW + szYb) {
    // att f32 direct to OUT; finkern RMW
    unsigned short* Yp = (unsigned short*)((char*)d_ws + szV + szSW);
    gemmT<false><<<dim3(576), dim3(256), 0, stream>>>(V, SW, out, Yp, nullptr, 0);
    finkern<false><<<dim3(BN / 4), dim3(256), 0, stream>>>(Yp, SW, nullptr, out);
  } else {
    // split fallback: att pass first (consumes V), then y pass with Yb alias V
    unsigned short* Yp = (unsigned short*)d_ws;
    gemmT<false><<<dim3(288), dim3(256), 0, stream>>>(V, SW, out, Yp, nullptr, 1);
    gemmT<false><<<dim3(288), dim3(256), 0, stream>>>(V, SW, out, Yp, nullptr, 2);
    finkern<false><<<dim3(BN / 4), dim3(256), 0, stream>>>(Yp, SW, nullptr, out);
  }
}